// Round 3
// baseline (544.778 us; speedup 1.0000x reference)
//
#include <hip/hip_runtime.h>
#include <hip/hip_bf16.h>
#include <math.h>

#define B_ 4
#define S_ 2048
#define D_ 1024
#define M_ (B_*S_)   // 8192 rows total across batch
#define MBYTE (1024ull*1024ull)

typedef __attribute__((ext_vector_type(8))) _Float16 f16x8;  // 8 f16 = 4 VGPRs (MFMA A/B frag)
typedef __attribute__((ext_vector_type(4))) float f32x4;     // MFMA C/D frag
typedef __attribute__((ext_vector_type(8))) unsigned short us8;
typedef unsigned short us;

__device__ inline us f2h(float f) {
    union { _Float16 h; us u; } x;
    x.h = (_Float16)f;   // RTE
    return x.u;
}
__device__ inline float h2f(us u) {
    union { us u; _Float16 h; } x; x.u = u;
    return (float)x.h;
}

__device__ inline void gload16(const us* g, us* l) {
    __builtin_amdgcn_global_load_lds(
        (const __attribute__((address_space(1))) unsigned int*)g,
        (__attribute__((address_space(3))) unsigned int*)l, 16, 0, 0);
}

// ---------------------------------------------------------------------------
// Split cast: f32 -> hi fp16 (+ lo fp16 residual if DO_LO). 4 elems/thread.
// Also used flat on Wk (row-major [d][e] is exactly the Bt operand of the
// W'^T = Wr^T @ Wk^T product).
// ---------------------------------------------------------------------------
template<int DO_LO>
__global__ __launch_bounds__(256)
void cast2_k(const float* __restrict__ in, us* __restrict__ hi, us* __restrict__ lo) {
    const size_t i = ((size_t)blockIdx.x * 256 + threadIdx.x) * 4;
    const float4 v = *(const float4*)&in[i];
    ushort4 h;
    h.x = f2h(v.x); h.y = f2h(v.y); h.z = f2h(v.z); h.w = f2h(v.w);
    *(ushort4*)&hi[i] = h;
    if (DO_LO) {
        ushort4 l;
        l.x = f2h(v.x - h2f(h.x)); l.y = f2h(v.y - h2f(h.y));
        l.z = f2h(v.z - h2f(h.z)); l.w = f2h(v.w - h2f(h.w));
        *(ushort4*)&lo[i] = l;
    }
}

// ---------------------------------------------------------------------------
// Weight transpose + split cast: W fp32 [K][N] -> Wt1(,Wt2) fp16 [N][K].
// ---------------------------------------------------------------------------
template<int DO_LO>
__global__ __launch_bounds__(256)
void wsplit_k(const float* __restrict__ W, us* __restrict__ Wt1, us* __restrict__ Wt2) {
    __shared__ float t[64][65];
    const int tid = threadIdx.x;
    const int k0 = blockIdx.x*64, n0 = blockIdx.y*64;
    #pragma unroll
    for (int i = 0; i < 4; ++i) {
        const int c = i*256 + tid;
        const int row = c >> 4, col = (c & 15) * 4;
        const float4 v = *(const float4*)&W[(size_t)(k0+row)*D_ + n0+col];
        t[row][col]=v.x; t[row][col+1]=v.y; t[row][col+2]=v.z; t[row][col+3]=v.w;
    }
    __syncthreads();
    #pragma unroll
    for (int i = 0; i < 4; ++i) {
        const int c = i*256 + tid;
        const int n = c >> 4, k = (c & 15) * 4;
        float f[4] = { t[k][n], t[k+1][n], t[k+2][n], t[k+3][n] };
        ushort4 h;
        h.x=f2h(f[0]); h.y=f2h(f[1]); h.z=f2h(f[2]); h.w=f2h(f[3]);
        *(ushort4*)&Wt1[(size_t)(n0+n)*D_ + k0+k] = h;
        if (DO_LO) {
            ushort4 l;
            l.x=f2h(f[0]-h2f(h.x)); l.y=f2h(f[1]-h2f(h.y));
            l.z=f2h(f[2]-h2f(h.z)); l.w=f2h(f[3]-h2f(h.w));
            *(ushort4*)&Wt2[(size_t)(n0+n)*D_ + k0+k] = l;
        }
    }
}

// ---------------------------------------------------------------------------
// b' = bk @ Wr + br  (fp32, 1024 outputs). Thread r accumulates over e with
// coalesced Wr[e][r] column reads; 4-way unrolled partial sums for ILP.
// ---------------------------------------------------------------------------
__global__ __launch_bounds__(256)
void bprime_k(const float* __restrict__ bk, const float* __restrict__ Wr,
              const float* __restrict__ br, float* __restrict__ bp) {
    const int r = blockIdx.x * 256 + threadIdx.x;
    float a0 = 0.f, a1 = 0.f, a2 = 0.f, a3 = 0.f;
    for (int e = 0; e < D_; e += 4) {
        a0 += bk[e+0] * Wr[(size_t)(e+0)*D_ + r];
        a1 += bk[e+1] * Wr[(size_t)(e+1)*D_ + r];
        a2 += bk[e+2] * Wr[(size_t)(e+2)*D_ + r];
        a3 += bk[e+3] * Wr[(size_t)(e+3)*D_ + r];
    }
    bp[r] = ((a0 + a1) + (a2 + a3)) + br[r];
}

// ---------------------------------------------------------------------------
// fp16 MFMA GEMM: C[M][N] = A[M][K] @ Bt[N][K]^T, fp32 accumulate.
// 128x128 tile, BK=64, 4 waves 2x2, global_load_lds width-16 staging.
// blockIdx.x = M-tile (XCD = blk%8 = m%8 -> A-panel L2 sharing on one XCD).
//
// SPLIT=1: A=A1+A2, B=B1+B2 (fp16 hi/lo); computes A1B1+A1B2+A2B1
//   (fp32-grade) with 4 LDS buffers and 3 MFMA per fragment quad.
//   ROUND-1 LESSON (do not redo): restructuring this as one virtual-K GEMM
//   over [A1,A1,A2]@[B1;B2;B1]^T regressed 127->264 us (400->195 TF):
//   grid is 512 blocks = 2 blocks/CU, so the smaller LDS bought NO
//   occupancy, while staged bytes rose 1.5x and MFMA-per-staged-byte fell
//   3x. In this staging-bound 2-barrier structure, MFMA density per staged
//   byte is the figure of merit -- the 4-buffer/3-MFMA form maximizes it.
//
// EPI: 0 = fp32 store (z-offset sC); 1 = f16(acc + colbias);
//      2 = f16(cos(acc + colbias)); 3 = split f16 store of (acc + colbias);
//      4 = f16(acc + ROW bias)  [direct-V^T epilogue].
// bias may be nullptr (treated as 0). f16 outputs apply z*sC element offset.
// Epilogue is LDS-staged so all global stores are 16B/lane coalesced.
// ---------------------------------------------------------------------------
template<int Nv, int Kv, int SPLIT, int EPI>
__global__ __launch_bounds__(256)
void gemm_bt_k(const us* __restrict__ A1, const us* __restrict__ A2,
               const us* __restrict__ B1, const us* __restrict__ B2,
               const float* __restrict__ bias, void* __restrict__ Cv,
               us* __restrict__ C2, long sA, long sB, long sC) {
    __shared__ us smem[(SPLIT?4:2)*128*64];
    us* As  = smem;                              // (+As2 if SPLIT)
    us* As2 = smem + 128*64;
    us* Bs  = smem + (SPLIT?2:1)*128*64;
    us* Bs2 = Bs + 128*64;
    const int tid = threadIdx.x;
    const us* A1b = A1 + (size_t)blockIdx.z * sA;
    const us* A2b = SPLIT ? A2 + (size_t)blockIdx.z * sA : nullptr;
    const us* B1b = B1 + (size_t)blockIdx.z * sB;
    const us* B2b = SPLIT ? B2 + (size_t)blockIdx.z * sB : nullptr;
    const int m0 = blockIdx.x * 128, n0 = blockIdx.y * 128;   // m on x: XCD swizzle
    const int lane = tid & 63, w = tid >> 6;
    const int mw = (w >> 1) * 64, nw = (w & 1) * 64;
    const int lr = lane & 15, lq = lane >> 4;

    const int crow = tid >> 3;          // staging row (0..31, +32/i)
    const int ccol = (tid & 7) * 8;     // staging col chunk (elems)

    f32x4 acc[4][4];
    #pragma unroll
    for (int i = 0; i < 4; ++i)
        #pragma unroll
        for (int j = 0; j < 4; ++j)
            acc[i][j] = (f32x4){0.f, 0.f, 0.f, 0.f};

    for (int kc = 0; kc < Kv; kc += 64) {
        #pragma unroll
        for (int i = 0; i < 4; ++i) {
            const int r = crow + i * 32;
            gload16(&A1b[(size_t)(m0 + r) * Kv + kc + ccol], &As[(size_t)(i*256 + tid) * 8]);
            gload16(&B1b[(size_t)(n0 + r) * Kv + kc + ccol], &Bs[(size_t)(i*256 + tid) * 8]);
            if (SPLIT) {
                gload16(&A2b[(size_t)(m0 + r) * Kv + kc + ccol], &As2[(size_t)(i*256 + tid) * 8]);
                gload16(&B2b[(size_t)(n0 + r) * Kv + kc + ccol], &Bs2[(size_t)(i*256 + tid) * 8]);
            }
        }
        __syncthreads();
        #pragma unroll
        for (int kk = 0; kk < 64; kk += 32) {
            f16x8 a1[4], b1[4];
            #pragma unroll
            for (int i = 0; i < 4; ++i)
                a1[i] = *(const f16x8*)&As[(mw + i*16 + lr) * 64 + kk + lq*8];
            #pragma unroll
            for (int j = 0; j < 4; ++j)
                b1[j] = *(const f16x8*)&Bs[(nw + j*16 + lr) * 64 + kk + lq*8];
            if (SPLIT) {
                f16x8 a2[4], b2[4];
                #pragma unroll
                for (int i = 0; i < 4; ++i)
                    a2[i] = *(const f16x8*)&As2[(mw + i*16 + lr) * 64 + kk + lq*8];
                #pragma unroll
                for (int j = 0; j < 4; ++j)
                    b2[j] = *(const f16x8*)&Bs2[(nw + j*16 + lr) * 64 + kk + lq*8];
                #pragma unroll
                for (int i = 0; i < 4; ++i)
                    #pragma unroll
                    for (int j = 0; j < 4; ++j) {
                        acc[i][j] = __builtin_amdgcn_mfma_f32_16x16x32_f16(a2[i], b1[j], acc[i][j], 0, 0, 0);
                        acc[i][j] = __builtin_amdgcn_mfma_f32_16x16x32_f16(a1[i], b2[j], acc[i][j], 0, 0, 0);
                        acc[i][j] = __builtin_amdgcn_mfma_f32_16x16x32_f16(a1[i], b1[j], acc[i][j], 0, 0, 0);
                    }
            } else {
                #pragma unroll
                for (int i = 0; i < 4; ++i)
                    #pragma unroll
                    for (int j = 0; j < 4; ++j)
                        acc[i][j] = __builtin_amdgcn_mfma_f32_16x16x32_f16(a1[i], b1[j], acc[i][j], 0, 0, 0);
            }
        }
        __syncthreads();
    }

    // ---------------- coalesced epilogue ----------------
    // Wave w owns quadrant rows [mw,mw+64) x cols [nw,nw+64). Stage 32 rows
    // at a time (per-wave 8 KB slab in the first 32 KB of smem), read back
    // row-major, store 16B/lane contiguous.
    float* slab = (float*)smem + (size_t)w * 2048;   // 32x64 fp32
    const int lrow0 = lane >> 3, cb = (lane & 7) * 8;
    #pragma unroll
    for (int p = 0; p < 2; ++p) {
        #pragma unroll
        for (int ii = 0; ii < 2; ++ii) {
            const int i = p*2 + ii;
            #pragma unroll
            for (int j = 0; j < 4; ++j)
                #pragma unroll
                for (int r = 0; r < 4; ++r)
                    slab[(ii*16 + lq*4 + r)*64 + j*16 + lr] = acc[i][j][r];
        }
        __syncthreads();
        #pragma unroll
        for (int t = 0; t < 4; ++t) {
            const int lrow = t*8 + lrow0;
            const int grow = m0 + mw + p*32 + lrow;
            const int gcol = n0 + nw + cb;
            const size_t idx = (size_t)grow * Nv + gcol;
            float v[8];
            #pragma unroll
            for (int u = 0; u < 8; ++u) v[u] = slab[lrow*64 + cb + u];
            if (EPI == 0) {
                float* Cf = (float*)Cv + (size_t)blockIdx.z * sC;
                float4 o0 = {v[0],v[1],v[2],v[3]}, o1 = {v[4],v[5],v[6],v[7]};
                *(float4*)&Cf[idx] = o0;
                *(float4*)&Cf[idx+4] = o1;
            } else if (EPI == 1 || EPI == 2) {
                us* Ch = (us*)Cv + (size_t)blockIdx.z * sC;
                us8 o;
                #pragma unroll
                for (int u = 0; u < 8; ++u) {
                    const float tv = v[u] + (bias ? bias[gcol + u] : 0.f);
                    o[u] = f2h(EPI == 2 ? cosf(tv) : tv);
                }
                *(us8*)&Ch[idx] = o;
            } else if (EPI == 4) {
                us* Ch = (us*)Cv + (size_t)blockIdx.z * sC;
                const float rb = bias ? bias[grow] : 0.f;
                us8 o;
                #pragma unroll
                for (int u = 0; u < 8; ++u) o[u] = f2h(v[u] + rb);
                *(us8*)&Ch[idx] = o;
            } else {
                us* Ch  = (us*)Cv + (size_t)blockIdx.z * sC;
                us* C2h = C2 + (size_t)blockIdx.z * sC;
                us8 oh, ol;
                #pragma unroll
                for (int u = 0; u < 8; ++u) {
                    const float tv = v[u] + (bias ? bias[gcol + u] : 0.f);
                    const us hh = f2h(tv);
                    oh[u] = hh;
                    ol[u] = f2h(tv - h2f(hh));
                }
                *(us8*)&Ch[idx] = oh;
                *(us8*)&C2h[idx] = ol;
            }
        }
        __syncthreads();
    }
}

// ---------------------------------------------------------------------------
// Row softmax: S fp32 [S_] per row -> normalized P fp16. One block per row.
// ---------------------------------------------------------------------------
__global__ __launch_bounds__(256)
void softmax_k(const float* __restrict__ S, us* __restrict__ P) {
    __shared__ float red[8];
    const int tid = threadIdx.x;
    const int lane = tid & 63, w = tid >> 6;
    const float* row = S + (size_t)blockIdx.x * S_;

    const float4 v0 = *(const float4*)&row[tid*8];
    const float4 v1 = *(const float4*)&row[tid*8 + 4];
    float e[8] = {v0.x, v0.y, v0.z, v0.w, v1.x, v1.y, v1.z, v1.w};

    float mx = e[0];
    #pragma unroll
    for (int j = 1; j < 8; ++j) mx = fmaxf(mx, e[j]);
    #pragma unroll
    for (int off = 1; off < 64; off <<= 1) mx = fmaxf(mx, __shfl_xor(mx, off));
    if (lane == 0) red[w] = mx;
    __syncthreads();
    mx = fmaxf(fmaxf(red[0], red[1]), fmaxf(red[2], red[3]));

    float sum = 0.f;
    #pragma unroll
    for (int j = 0; j < 8; ++j) { e[j] = __expf(e[j] - mx); sum += e[j]; }
    #pragma unroll
    for (int off = 1; off < 64; off <<= 1) sum += __shfl_xor(sum, off);
    if (lane == 0) red[4 + w] = sum;
    __syncthreads();
    const float inv = 1.0f / (red[4] + red[5] + red[6] + red[7]);

    us8 o;
    #pragma unroll
    for (int j = 0; j < 8; ++j) o[j] = f2h(e[j] * inv);
    *(us8*)&P[(size_t)blockIdx.x * S_ + tid*8] = o;
}

// ---------------------------------------------------------------------------
extern "C" void kernel_launch(void* const* d_in, const int* in_sizes, int n_in,
                              void* d_out, int out_size, void* d_ws, size_t ws_size,
                              hipStream_t stream) {
    const float* x  = (const float*)d_in[0];
    const float* y  = (const float*)d_in[1];
    const float* Wq = (const float*)d_in[2];
    const float* bq = (const float*)d_in[3];
    const float* Wk = (const float*)d_in[4];
    const float* bk = (const float*)d_in[5];
    const float* Wv = (const float*)d_in[6];
    const float* bv = (const float*)d_in[7];
    const float* Wr = (const float*)d_in[8];
    const float* br = (const float*)d_in[9];
    float* out = (float*)d_out;

    // ALGEBRAIC FUSION (round 3): cos((y@Wk+bk)@Wr+br) = cos(y@W' + b') with
    // W' = Wk@Wr (1024^3 split GEMM, 64 blocks, ~20us) and b' = bk@Wr + br.
    // Removes one full 8192-row split GEMM (~128us measured). W' is computed
    // to fp32-grade (split-fp16), so cos-argument error (~2^-22) is far
    // below the fp16 attention-path noise that sets absmax.
    //
    // Workspace choreography (96 MB). Liveness-checked (MB):
    //  [ 0,16) y1                         live: cast .. V^T gemm
    //  [16,32) y2 -> xh -> P(b0,b1)
    //  [32,48) Qb -> P(b2,b3)
    //  [48,64) Kh
    //  [64,96) small weights / W' / S2 (32 MB fp32) -> Vt@64, Wv1@80
    //   detail: Wkf1@64 Wkf2@66 Wr1@68 Wr2@70 WT1@72 WT2@74 bp@76 (dead
    //   before Q chain); Wq1@64 (dead before scores); S2@64 during scores.
    // Pair {0,1} scores run FIRST (P01 lands @16 after xh dies); pair {2,3}
    // second (P23 @32 after Qb dies) -> P contiguous 0..3 -> one z=4 PV.
    char* wsb = (char*)d_ws;
    us*    y1   = (us*)(wsb +  0*MBYTE);
    us*    y2   = (us*)(wsb + 16*MBYTE);
    us*    xh   = (us*)(wsb + 16*MBYTE);
    us*    Pb   = (us*)(wsb + 16*MBYTE);  // P batches 0..3 contiguous [16,48)
    us*    Qb   = (us*)(wsb + 32*MBYTE);
    us*    P23  = (us*)(wsb + 32*MBYTE);
    us*    Kh   = (us*)(wsb + 48*MBYTE);
    us*    Wkf1 = (us*)(wsb + 64*MBYTE);
    us*    Wkf2 = (us*)(wsb + 66*MBYTE);
    us*    Wr1  = (us*)(wsb + 68*MBYTE);
    us*    Wr2  = (us*)(wsb + 70*MBYTE);
    us*    WT1  = (us*)(wsb + 72*MBYTE);
    us*    WT2  = (us*)(wsb + 74*MBYTE);
    float* bp   = (float*)(wsb + 76*MBYTE);
    us*    Wq1  = (us*)(wsb + 64*MBYTE);
    float* S2   = (float*)(wsb + 64*MBYTE); // 32 MB, reused per batch pair
    us*    Vt   = (us*)(wsb + 64*MBYTE);    // [b][d][s] 16 MB
    us*    Wv1  = (us*)(wsb + 80*MBYTE);

    const dim3 bb(256);
    const dim3 gcast(M_*D_/1024), gcastW(D_*D_/1024), gw(16,16);
    const dim3 gproj(M_/128, D_/128);            // m on x -> XCD A-panel sharing

    // --- K-hat chain: W' = Wk@Wr, b' = bk@Wr + br, Kh = cos(y@W' + b') ---
    cast2_k<1><<<gcast, bb, 0, stream>>>(y, y1, y2);
    cast2_k<1><<<gcastW, bb, 0, stream>>>(Wk, Wkf1, Wkf2);   // [d][e] flat
    wsplit_k<1><<<gw, bb, 0, stream>>>(Wr, Wr1, Wr2);        // [r][e]
    bprime_k<<<dim3(D_/256), bb, 0, stream>>>(bk, Wr, br, bp);
    // W'^T[r][d] = sum_e Wr^T[r][e] * Wk[d][e]  (A=Wr^T, Bt=Wk row-major)
    gemm_bt_k<D_, D_, 1, 3><<<dim3(D_/128, D_/128), bb, 0, stream>>>(
        Wr1, Wr2, Wkf1, Wkf2, nullptr, (void*)WT1, WT2, 0, 0, 0);
    // Kh[s][r] = cos(y@W' + b')  — one 8192-row split GEMM (was two)
    gemm_bt_k<D_, D_, 1, 2><<<gproj, bb, 0, stream>>>(
        y1, y2, WT1, WT2, bp, (void*)Kh, nullptr, 0, 0, 0);

    // --- Q ---
    cast2_k<0><<<gcast, bb, 0, stream>>>(x, xh, nullptr);
    wsplit_k<0><<<gw, bb, 0, stream>>>(Wq, Wq1, nullptr);
    gemm_bt_k<D_, D_, 0, 1><<<gproj, bb, 0, stream>>>(
        xh, nullptr, Wq1, nullptr, bq, (void*)Qb, nullptr, 0, 0, 0);

    // --- attention scores + softmax, batch pairs (z=2 -> 512 blocks, 2/CU).
    //     Pair {0,1} first (see layout). ---
    gemm_bt_k<S_, D_, 0, 0><<<dim3(S_/128, S_/128, 2), bb, 0, stream>>>(
        Qb, nullptr, Kh, nullptr,
        nullptr, (void*)S2, nullptr, (long)S_*D_, (long)S_*D_, (long)S_*S_);
    softmax_k<<<dim3(2*S_), bb, 0, stream>>>(S2, Pb);
    gemm_bt_k<S_, D_, 0, 0><<<dim3(S_/128, S_/128, 2), bb, 0, stream>>>(
        Qb + 2*(size_t)S_*D_, nullptr, Kh + 2*(size_t)S_*D_, nullptr,
        nullptr, (void*)S2, nullptr, (long)S_*D_, (long)S_*D_, (long)S_*S_);
    softmax_k<<<dim3(2*S_), bb, 0, stream>>>(S2, P23);

    // --- V^T directly: Vt[b][d][s] = sum_e Wv^T[d][e]*y[b][s][e] + bv[d]
    //     (EPI=4 row bias; removes vtrans + Vh round-trip; same numerics) ---
    wsplit_k<0><<<gw, bb, 0, stream>>>(Wv, Wv1, nullptr);
    gemm_bt_k<S_, D_, 0, 4><<<dim3(D_/128, S_/128, B_), bb, 0, stream>>>(
        Wv1, nullptr, y1, nullptr, bv, (void*)Vt, nullptr,
        0, (long)S_*D_, (long)D_*S_);

    // --- PV: single z=4 dispatch, P contiguous in batch order ---
    gemm_bt_k<D_, S_, 0, 0><<<dim3(S_/128, D_/128, B_), bb, 0, stream>>>(
        Pb, nullptr, Vt, nullptr, nullptr, (void*)out, nullptr,
        (long)S_*S_, (long)D_*S_, (long)S_*D_);
}

// Round 4
// 489.448 us; speedup vs baseline: 1.1130x; 1.1130x over previous
//
#include <hip/hip_runtime.h>
#include <hip/hip_bf16.h>
#include <math.h>

#define B_ 4
#define S_ 2048
#define D_ 1024
#define M_ (B_*S_)   // 8192 rows total across batch
#define MBYTE (1024ull*1024ull)

typedef __attribute__((ext_vector_type(8))) _Float16 f16x8;  // 8 f16 = 4 VGPRs (MFMA A/B frag)
typedef __attribute__((ext_vector_type(4))) float f32x4;     // MFMA C/D frag
typedef __attribute__((ext_vector_type(8))) unsigned short us8;
typedef unsigned short us;

__device__ inline us f2h(float f) {
    union { _Float16 h; us u; } x;
    x.h = (_Float16)f;   // RTE
    return x.u;
}
__device__ inline float h2f(us u) {
    union { us u; _Float16 h; } x; x.u = u;
    return (float)x.h;
}

__device__ inline void gload16(const us* g, us* l) {
    __builtin_amdgcn_global_load_lds(
        (const __attribute__((address_space(1))) unsigned int*)g,
        (__attribute__((address_space(3))) unsigned int*)l, 16, 0, 0);
}

// ---------------------------------------------------------------------------
// Split cast: f32 -> hi fp16 (+ lo fp16 residual if DO_LO). 4 elems/thread.
// Also used flat on Wk (row-major [d][e] is exactly the Bt operand of the
// W'^T = Wr^T @ Wk^T product).
// ---------------------------------------------------------------------------
template<int DO_LO>
__global__ __launch_bounds__(256)
void cast2_k(const float* __restrict__ in, us* __restrict__ hi, us* __restrict__ lo) {
    const size_t i = ((size_t)blockIdx.x * 256 + threadIdx.x) * 4;
    const float4 v = *(const float4*)&in[i];
    ushort4 h;
    h.x = f2h(v.x); h.y = f2h(v.y); h.z = f2h(v.z); h.w = f2h(v.w);
    *(ushort4*)&hi[i] = h;
    if (DO_LO) {
        ushort4 l;
        l.x = f2h(v.x - h2f(h.x)); l.y = f2h(v.y - h2f(h.y));
        l.z = f2h(v.z - h2f(h.z)); l.w = f2h(v.w - h2f(h.w));
        *(ushort4*)&lo[i] = l;
    }
}

// ---------------------------------------------------------------------------
// Weight transpose + split cast: W fp32 [K][N] -> Wt1(,Wt2) fp16 [N][K].
// ---------------------------------------------------------------------------
template<int DO_LO>
__global__ __launch_bounds__(256)
void wsplit_k(const float* __restrict__ W, us* __restrict__ Wt1, us* __restrict__ Wt2) {
    __shared__ float t[64][65];
    const int tid = threadIdx.x;
    const int k0 = blockIdx.x*64, n0 = blockIdx.y*64;
    #pragma unroll
    for (int i = 0; i < 4; ++i) {
        const int c = i*256 + tid;
        const int row = c >> 4, col = (c & 15) * 4;
        const float4 v = *(const float4*)&W[(size_t)(k0+row)*D_ + n0+col];
        t[row][col]=v.x; t[row][col+1]=v.y; t[row][col+2]=v.z; t[row][col+3]=v.w;
    }
    __syncthreads();
    #pragma unroll
    for (int i = 0; i < 4; ++i) {
        const int c = i*256 + tid;
        const int n = c >> 4, k = (c & 15) * 4;
        float f[4] = { t[k][n], t[k+1][n], t[k+2][n], t[k+3][n] };
        ushort4 h;
        h.x=f2h(f[0]); h.y=f2h(f[1]); h.z=f2h(f[2]); h.w=f2h(f[3]);
        *(ushort4*)&Wt1[(size_t)(n0+n)*D_ + k0+k] = h;
        if (DO_LO) {
            ushort4 l;
            l.x=f2h(f[0]-h2f(h.x)); l.y=f2h(f[1]-h2f(h.y));
            l.z=f2h(f[2]-h2f(h.z)); l.w=f2h(f[3]-h2f(h.w));
            *(ushort4*)&Wt2[(size_t)(n0+n)*D_ + k0+k] = l;
        }
    }
}

// ---------------------------------------------------------------------------
// Reduce 8 fp32 K-split partial slabs of W' and emit hi/lo split fp16.
// 1024 blocks; 32 MB read / 4 MB written, ~8 us.
// ---------------------------------------------------------------------------
__global__ __launch_bounds__(256)
void wreduce_k(const float* __restrict__ Wp, us* __restrict__ W1, us* __restrict__ W2) {
    const size_t i = ((size_t)blockIdx.x * 256 + threadIdx.x) * 4;
    float4 s = *(const float4*)&Wp[i];
    #pragma unroll
    for (int z = 1; z < 8; ++z) {
        const float4 v = *(const float4*)&Wp[(size_t)z*D_*D_ + i];
        s.x += v.x; s.y += v.y; s.z += v.z; s.w += v.w;
    }
    ushort4 h, l;
    h.x=f2h(s.x); h.y=f2h(s.y); h.z=f2h(s.z); h.w=f2h(s.w);
    l.x=f2h(s.x-h2f(h.x)); l.y=f2h(s.y-h2f(h.y));
    l.z=f2h(s.z-h2f(h.z)); l.w=f2h(s.w-h2f(h.w));
    *(ushort4*)&W1[i] = h;
    *(ushort4*)&W2[i] = l;
}

// ---------------------------------------------------------------------------
// b' = bk @ Wr + br. ROUND-3 LESSON: the 4-block version was latency-bound
// (~30-40us, 4 CUs streaming 4MB). Now: bpinit seeds bp=br, then (4,16)
// e-chunked partial sums with device-scope atomicAdd -> 64 blocks, ~5us.
// ---------------------------------------------------------------------------
__global__ __launch_bounds__(256)
void bpinit_k(const float* __restrict__ br, float* __restrict__ bp) {
    const int r = blockIdx.x * 256 + threadIdx.x;
    bp[r] = br[r];
}
__global__ __launch_bounds__(256)
void bprime_k(const float* __restrict__ bk, const float* __restrict__ Wr,
              float* __restrict__ bp) {
    const int r = blockIdx.x * 256 + threadIdx.x;
    const int e0 = blockIdx.y * 64;
    float a0 = 0.f, a1 = 0.f, a2 = 0.f, a3 = 0.f;
    for (int e = e0; e < e0 + 64; e += 4) {
        a0 += bk[e+0] * Wr[(size_t)(e+0)*D_ + r];
        a1 += bk[e+1] * Wr[(size_t)(e+1)*D_ + r];
        a2 += bk[e+2] * Wr[(size_t)(e+2)*D_ + r];
        a3 += bk[e+3] * Wr[(size_t)(e+3)*D_ + r];
    }
    atomicAdd(&bp[r], (a0 + a1) + (a2 + a3));
}

// ---------------------------------------------------------------------------
// fp16 MFMA GEMM: C[M][N] = A[M][K] @ Bt[N][K]^T, fp32 accumulate.
// 128x128 tile, BK=64, 4 waves 2x2, global_load_lds width-16 staging.
// blockIdx.x = M-tile (XCD = blk%8 = m%8 -> A-panel L2 sharing on one XCD).
//
// SPLIT=1: A=A1+A2, B=B1+B2 (fp16 hi/lo); computes A1B1+A1B2+A2B1
//   (fp32-grade) with 4 LDS buffers and 3 MFMA per fragment quad.
//   ROUND-1 LESSON (do not redo): virtual-K restructure regressed 127->264us
//   (staged bytes +50%, MFMA-per-staged-byte /3, occupancy unchanged).
//
// KS>1: K-split -- blockIdx.z selects a K-chunk of Kv/KS (batch offsets
//   disabled via sA=sB=0; EPI=0 writes a per-z fp32 slab at z*sC).
//   ROUND-3 LESSON: a 64-block GEMM (1 block on 1/4 of CUs) is latency-
//   bound at 0.6% occupancy -- 155us for 1024^3. K-split x8 -> 512 blocks
//   = 2/CU restores the TLP this 2-barrier structure needs.
//
// EPI: 0 = fp32 store (z-offset sC); 1 = f16(acc + colbias);
//      2 = f16(cos(acc + colbias)); 3 = split f16 store of (acc + colbias);
//      4 = f16(acc + ROW bias)  [direct-V^T epilogue].
// bias may be nullptr (treated as 0). f16 outputs apply z*sC element offset.
// Epilogue is LDS-staged so all global stores are 16B/lane coalesced.
// ---------------------------------------------------------------------------
template<int Nv, int Kv, int SPLIT, int EPI, int KS>
__global__ __launch_bounds__(256)
void gemm_bt_k(const us* __restrict__ A1, const us* __restrict__ A2,
               const us* __restrict__ B1, const us* __restrict__ B2,
               const float* __restrict__ bias, void* __restrict__ Cv,
               us* __restrict__ C2, long sA, long sB, long sC) {
    __shared__ us smem[(SPLIT?4:2)*128*64];
    us* As  = smem;                              // (+As2 if SPLIT)
    us* As2 = smem + 128*64;
    us* Bs  = smem + (SPLIT?2:1)*128*64;
    us* Bs2 = Bs + 128*64;
    const int tid = threadIdx.x;
    const us* A1b = A1 + (size_t)blockIdx.z * sA;
    const us* A2b = SPLIT ? A2 + (size_t)blockIdx.z * sA : nullptr;
    const us* B1b = B1 + (size_t)blockIdx.z * sB;
    const us* B2b = SPLIT ? B2 + (size_t)blockIdx.z * sB : nullptr;
    const int m0 = blockIdx.x * 128, n0 = blockIdx.y * 128;   // m on x: XCD swizzle
    const int lane = tid & 63, w = tid >> 6;
    const int mw = (w >> 1) * 64, nw = (w & 1) * 64;
    const int lr = lane & 15, lq = lane >> 4;

    const int crow = tid >> 3;          // staging row (0..31, +32/i)
    const int ccol = (tid & 7) * 8;     // staging col chunk (elems)

    f32x4 acc[4][4];
    #pragma unroll
    for (int i = 0; i < 4; ++i)
        #pragma unroll
        for (int j = 0; j < 4; ++j)
            acc[i][j] = (f32x4){0.f, 0.f, 0.f, 0.f};

    int kc0 = 0, kc1 = Kv;
    if (KS > 1) {
        const int kchunk = Kv / KS;
        kc0 = blockIdx.z * kchunk;
        kc1 = kc0 + kchunk;
    }
    for (int kc = kc0; kc < kc1; kc += 64) {
        #pragma unroll
        for (int i = 0; i < 4; ++i) {
            const int r = crow + i * 32;
            gload16(&A1b[(size_t)(m0 + r) * Kv + kc + ccol], &As[(size_t)(i*256 + tid) * 8]);
            gload16(&B1b[(size_t)(n0 + r) * Kv + kc + ccol], &Bs[(size_t)(i*256 + tid) * 8]);
            if (SPLIT) {
                gload16(&A2b[(size_t)(m0 + r) * Kv + kc + ccol], &As2[(size_t)(i*256 + tid) * 8]);
                gload16(&B2b[(size_t)(n0 + r) * Kv + kc + ccol], &Bs2[(size_t)(i*256 + tid) * 8]);
            }
        }
        __syncthreads();
        #pragma unroll
        for (int kk = 0; kk < 64; kk += 32) {
            f16x8 a1[4], b1[4];
            #pragma unroll
            for (int i = 0; i < 4; ++i)
                a1[i] = *(const f16x8*)&As[(mw + i*16 + lr) * 64 + kk + lq*8];
            #pragma unroll
            for (int j = 0; j < 4; ++j)
                b1[j] = *(const f16x8*)&Bs[(nw + j*16 + lr) * 64 + kk + lq*8];
            if (SPLIT) {
                f16x8 a2[4], b2[4];
                #pragma unroll
                for (int i = 0; i < 4; ++i)
                    a2[i] = *(const f16x8*)&As2[(mw + i*16 + lr) * 64 + kk + lq*8];
                #pragma unroll
                for (int j = 0; j < 4; ++j)
                    b2[j] = *(const f16x8*)&Bs2[(nw + j*16 + lr) * 64 + kk + lq*8];
                #pragma unroll
                for (int i = 0; i < 4; ++i)
                    #pragma unroll
                    for (int j = 0; j < 4; ++j) {
                        acc[i][j] = __builtin_amdgcn_mfma_f32_16x16x32_f16(a2[i], b1[j], acc[i][j], 0, 0, 0);
                        acc[i][j] = __builtin_amdgcn_mfma_f32_16x16x32_f16(a1[i], b2[j], acc[i][j], 0, 0, 0);
                        acc[i][j] = __builtin_amdgcn_mfma_f32_16x16x32_f16(a1[i], b1[j], acc[i][j], 0, 0, 0);
                    }
            } else {
                #pragma unroll
                for (int i = 0; i < 4; ++i)
                    #pragma unroll
                    for (int j = 0; j < 4; ++j)
                        acc[i][j] = __builtin_amdgcn_mfma_f32_16x16x32_f16(a1[i], b1[j], acc[i][j], 0, 0, 0);
            }
        }
        __syncthreads();
    }

    // ---------------- coalesced epilogue ----------------
    // Wave w owns quadrant rows [mw,mw+64) x cols [nw,nw+64). Stage 32 rows
    // at a time (per-wave 8 KB slab in the first 32 KB of smem), read back
    // row-major, store 16B/lane contiguous.
    float* slab = (float*)smem + (size_t)w * 2048;   // 32x64 fp32
    const int lrow0 = lane >> 3, cb = (lane & 7) * 8;
    #pragma unroll
    for (int p = 0; p < 2; ++p) {
        #pragma unroll
        for (int ii = 0; ii < 2; ++ii) {
            const int i = p*2 + ii;
            #pragma unroll
            for (int j = 0; j < 4; ++j)
                #pragma unroll
                for (int r = 0; r < 4; ++r)
                    slab[(ii*16 + lq*4 + r)*64 + j*16 + lr] = acc[i][j][r];
        }
        __syncthreads();
        #pragma unroll
        for (int t = 0; t < 4; ++t) {
            const int lrow = t*8 + lrow0;
            const int grow = m0 + mw + p*32 + lrow;
            const int gcol = n0 + nw + cb;
            const size_t idx = (size_t)grow * Nv + gcol;
            float v[8];
            #pragma unroll
            for (int u = 0; u < 8; ++u) v[u] = slab[lrow*64 + cb + u];
            if (EPI == 0) {
                float* Cf = (float*)Cv + (size_t)blockIdx.z * sC;
                float4 o0 = {v[0],v[1],v[2],v[3]}, o1 = {v[4],v[5],v[6],v[7]};
                *(float4*)&Cf[idx] = o0;
                *(float4*)&Cf[idx+4] = o1;
            } else if (EPI == 1 || EPI == 2) {
                us* Ch = (us*)Cv + (size_t)blockIdx.z * sC;
                us8 o;
                #pragma unroll
                for (int u = 0; u < 8; ++u) {
                    const float tv = v[u] + (bias ? bias[gcol + u] : 0.f);
                    o[u] = f2h(EPI == 2 ? cosf(tv) : tv);
                }
                *(us8*)&Ch[idx] = o;
            } else if (EPI == 4) {
                us* Ch = (us*)Cv + (size_t)blockIdx.z * sC;
                const float rb = bias ? bias[grow] : 0.f;
                us8 o;
                #pragma unroll
                for (int u = 0; u < 8; ++u) o[u] = f2h(v[u] + rb);
                *(us8*)&Ch[idx] = o;
            } else {
                us* Ch  = (us*)Cv + (size_t)blockIdx.z * sC;
                us* C2h = C2 + (size_t)blockIdx.z * sC;
                us8 oh, ol;
                #pragma unroll
                for (int u = 0; u < 8; ++u) {
                    const float tv = v[u] + (bias ? bias[gcol + u] : 0.f);
                    const us hh = f2h(tv);
                    oh[u] = hh;
                    ol[u] = f2h(tv - h2f(hh));
                }
                *(us8*)&Ch[idx] = oh;
                *(us8*)&C2h[idx] = ol;
            }
        }
        __syncthreads();
    }
}

// ---------------------------------------------------------------------------
// Row softmax: S fp32 [S_] per row -> normalized P fp16. One block per row.
// ---------------------------------------------------------------------------
__global__ __launch_bounds__(256)
void softmax_k(const float* __restrict__ S, us* __restrict__ P) {
    __shared__ float red[8];
    const int tid = threadIdx.x;
    const int lane = tid & 63, w = tid >> 6;
    const float* row = S + (size_t)blockIdx.x * S_;

    const float4 v0 = *(const float4*)&row[tid*8];
    const float4 v1 = *(const float4*)&row[tid*8 + 4];
    float e[8] = {v0.x, v0.y, v0.z, v0.w, v1.x, v1.y, v1.z, v1.w};

    float mx = e[0];
    #pragma unroll
    for (int j = 1; j < 8; ++j) mx = fmaxf(mx, e[j]);
    #pragma unroll
    for (int off = 1; off < 64; off <<= 1) mx = fmaxf(mx, __shfl_xor(mx, off));
    if (lane == 0) red[w] = mx;
    __syncthreads();
    mx = fmaxf(fmaxf(red[0], red[1]), fmaxf(red[2], red[3]));

    float sum = 0.f;
    #pragma unroll
    for (int j = 0; j < 8; ++j) { e[j] = __expf(e[j] - mx); sum += e[j]; }
    #pragma unroll
    for (int off = 1; off < 64; off <<= 1) sum += __shfl_xor(sum, off);
    if (lane == 0) red[4 + w] = sum;
    __syncthreads();
    const float inv = 1.0f / (red[4] + red[5] + red[6] + red[7]);

    us8 o;
    #pragma unroll
    for (int j = 0; j < 8; ++j) o[j] = f2h(e[j] * inv);
    *(us8*)&P[(size_t)blockIdx.x * S_ + tid*8] = o;
}

// ---------------------------------------------------------------------------
extern "C" void kernel_launch(void* const* d_in, const int* in_sizes, int n_in,
                              void* d_out, int out_size, void* d_ws, size_t ws_size,
                              hipStream_t stream) {
    const float* x  = (const float*)d_in[0];
    const float* y  = (const float*)d_in[1];
    const float* Wq = (const float*)d_in[2];
    const float* bq = (const float*)d_in[3];
    const float* Wk = (const float*)d_in[4];
    const float* bk = (const float*)d_in[5];
    const float* Wv = (const float*)d_in[6];
    const float* bv = (const float*)d_in[7];
    const float* Wr = (const float*)d_in[8];
    const float* br = (const float*)d_in[9];
    float* out = (float*)d_out;

    // ALGEBRAIC FUSION: cos((y@Wk+bk)@Wr+br) = cos(y@W' + b'), W' = Wk@Wr,
    // b' = bk@Wr + br. Removes one 8192-row split GEMM (~128us measured).
    // ROUND-3 LESSON: the 1024^3 W' GEMM must be K-split (z=8 -> 512 blocks);
    // at 64 blocks it was latency-bound at 0.64% occupancy (155us).
    //
    // Workspace choreography (96 MB). Liveness-checked (MB):
    //  [ 0,16) y1                         live: cast .. V^T gemm
    //  [16,32) y2 -> xh -> P(b0,b1)
    //  [32,48) {Wp lo half} -> Qb -> P(b2,b3)
    //  [48,64) {Wp hi half} -> Kh
    //  [64,96) Wkf1@64 Wkf2@66 Wr1@68 Wr2@70 WT1@72 WT2@74 bp@76
    //          -> Wq1@64 -> S2@64 (32 MB) -> Vt@64 (16 MB), Wv1@80
    //  Wp (8 fp32 slabs, 32 MB) occupies [32,64) only during the W' chain;
    //  dead before Qb (Q GEMM) and Kh (Kh GEMM) are written.
    // Pair {0,1} scores run FIRST (P01 lands @16 after xh dies); pair {2,3}
    // second (P23 @32 after Qb dies) -> P contiguous 0..3 -> one z=4 PV.
    char* wsb = (char*)d_ws;
    us*    y1   = (us*)(wsb +  0*MBYTE);
    us*    y2   = (us*)(wsb + 16*MBYTE);
    us*    xh   = (us*)(wsb + 16*MBYTE);
    us*    Pb   = (us*)(wsb + 16*MBYTE);  // P batches 0..3 contiguous [16,48)
    float* Wp   = (float*)(wsb + 32*MBYTE); // 8 x 4MB fp32 K-split partials
    us*    Qb   = (us*)(wsb + 32*MBYTE);
    us*    P23  = (us*)(wsb + 32*MBYTE);
    us*    Kh   = (us*)(wsb + 48*MBYTE);
    us*    Wkf1 = (us*)(wsb + 64*MBYTE);
    us*    Wkf2 = (us*)(wsb + 66*MBYTE);
    us*    Wr1  = (us*)(wsb + 68*MBYTE);
    us*    Wr2  = (us*)(wsb + 70*MBYTE);
    us*    WT1  = (us*)(wsb + 72*MBYTE);
    us*    WT2  = (us*)(wsb + 74*MBYTE);
    float* bp   = (float*)(wsb + 76*MBYTE);
    us*    Wq1  = (us*)(wsb + 64*MBYTE);
    float* S2   = (float*)(wsb + 64*MBYTE); // 32 MB, reused per batch pair
    us*    Vt   = (us*)(wsb + 64*MBYTE);    // [b][d][s] 16 MB
    us*    Wv1  = (us*)(wsb + 80*MBYTE);

    const dim3 bb(256);
    const dim3 gcast(M_*D_/1024), gcastW(D_*D_/1024), gw(16,16);
    const dim3 gproj(M_/128, D_/128);            // m on x -> XCD A-panel sharing

    // --- K-hat chain: W' = Wk@Wr (K-split x8 + reduce), b' = bk@Wr + br,
    //     Kh = cos(y@W' + b') ---
    cast2_k<1><<<gcast, bb, 0, stream>>>(y, y1, y2);
    cast2_k<1><<<gcastW, bb, 0, stream>>>(Wk, Wkf1, Wkf2);   // [d][e] flat
    wsplit_k<1><<<gw, bb, 0, stream>>>(Wr, Wr1, Wr2);        // [r][e]
    bpinit_k<<<dim3(D_/256), bb, 0, stream>>>(br, bp);
    bprime_k<<<dim3(D_/256, 16), bb, 0, stream>>>(bk, Wr, bp);
    // W'^T[r][d] = sum_e Wr^T[r][e] * Wk[d][e], K-split z=8 -> fp32 slabs
    gemm_bt_k<D_, D_, 1, 0, 8><<<dim3(D_/128, D_/128, 8), bb, 0, stream>>>(
        Wr1, Wr2, Wkf1, Wkf2, nullptr, (void*)Wp, nullptr,
        0, 0, (long)D_*D_);
    wreduce_k<<<dim3(D_*D_/1024), bb, 0, stream>>>(Wp, WT1, WT2);
    // Kh[s][r] = cos(y@W' + b')  — one 8192-row split GEMM (was two)
    gemm_bt_k<D_, D_, 1, 2, 1><<<gproj, bb, 0, stream>>>(
        y1, y2, WT1, WT2, bp, (void*)Kh, nullptr, 0, 0, 0);

    // --- Q ---
    cast2_k<0><<<gcast, bb, 0, stream>>>(x, xh, nullptr);
    wsplit_k<0><<<gw, bb, 0, stream>>>(Wq, Wq1, nullptr);
    gemm_bt_k<D_, D_, 0, 1, 1><<<gproj, bb, 0, stream>>>(
        xh, nullptr, Wq1, nullptr, bq, (void*)Qb, nullptr, 0, 0, 0);

    // --- attention scores + softmax, batch pairs (z=2 -> 512 blocks, 2/CU).
    //     Pair {0,1} first (see layout). ---
    gemm_bt_k<S_, D_, 0, 0, 1><<<dim3(S_/128, S_/128, 2), bb, 0, stream>>>(
        Qb, nullptr, Kh, nullptr,
        nullptr, (void*)S2, nullptr, (long)S_*D_, (long)S_*D_, (long)S_*S_);
    softmax_k<<<dim3(2*S_), bb, 0, stream>>>(S2, Pb);
    gemm_bt_k<S_, D_, 0, 0, 1><<<dim3(S_/128, S_/128, 2), bb, 0, stream>>>(
        Qb + 2*(size_t)S_*D_, nullptr, Kh + 2*(size_t)S_*D_, nullptr,
        nullptr, (void*)S2, nullptr, (long)S_*D_, (long)S_*D_, (long)S_*S_);
    softmax_k<<<dim3(2*S_), bb, 0, stream>>>(S2, P23);

    // --- V^T directly: Vt[b][d][s] = sum_e Wv^T[d][e]*y[b][s][e] + bv[d]
    //     (EPI=4 row bias; removes vtrans + Vh round-trip; same numerics) ---
    wsplit_k<0><<<gw, bb, 0, stream>>>(Wv, Wv1, nullptr);
    gemm_bt_k<S_, D_, 0, 4, 1><<<dim3(D_/128, S_/128, B_), bb, 0, stream>>>(
        Wv1, nullptr, y1, nullptr, bv, (void*)Vt, nullptr,
        0, (long)S_*D_, (long)D_*S_);

    // --- PV: single z=4 dispatch, P contiguous in batch order ---
    gemm_bt_k<D_, S_, 0, 0, 1><<<dim3(S_/128, D_/128, B_), bb, 0, stream>>>(
        Pb, nullptr, Vt, nullptr, nullptr, (void*)out, nullptr,
        (long)S_*S_, (long)D_*S_, (long)S_*D_);
}